// Round 9
// baseline (682.092 us; speedup 1.0000x reference)
//
#include <hip/hip_runtime.h>
#include <hip/hip_cooperative_groups.h>
#include <cmath>

namespace cg = cooperative_groups;

#define IN_CH 128
#define OUT_CH 128
#define KDIM 512           // Z row: x(128) | sum(128) | mean(128) | max(128)
#define NGEMM 384          // W^T rows: permuted (colgroup, wavehalf, section, ocol16)
#define GBM 256            // fallback gemm rows per block
#define GBMP 448           // pipe gemm rows per block (single-round packing)
#define GBN 192            // gemm cols (W^T rows) per block
#define SLOT_B 53248       // pipe slot bytes: A 28K | Bhi 12K | Blo 12K
#define SLOT_US 26624
#define SB_SLOT_US 20480   // fallback single-buffer slot
#define PIPE_LDS_BYTES (3 * SLOT_B)   // D=3 ring = 159744 B <= 160 KiB

typedef __attribute__((ext_vector_type(8))) short bfrag;   // 8 bf16 in 4 VGPRs
typedef __attribute__((ext_vector_type(4))) float f32x4;

// float -> bf16 round-to-nearest-even (bit pattern)
__device__ __forceinline__ unsigned short f2bf(float f) {
    unsigned int u = __float_as_uint(f);
    return (unsigned short)((u + 0x7FFFu + ((u >> 16) & 1u)) >> 16);
}
__device__ __forceinline__ float bf2f(unsigned short h) {
    return __uint_as_float(((unsigned int)h) << 16);
}
__device__ __forceinline__ float4 unpack4(uint2 u) {
    float4 r;
    r.x = __uint_as_float(u.x << 16);
    r.y = __uint_as_float(u.x & 0xFFFF0000u);
    r.z = __uint_as_float(u.y << 16);
    r.w = __uint_as_float(u.y & 0xFFFF0000u);
    return r;
}

// async 16B global->LDS (wave-level; LDS side is lane-linear base+lane*16)
__device__ __forceinline__ void gl2lds16(const void* g, void* l) {
    __builtin_amdgcn_global_load_lds(
        (const __attribute__((address_space(1))) unsigned int*)g,
        (__attribute__((address_space(3))) unsigned int*)l, 16, 0, 0);
}

// ---------------- agg body (shared by coop phase 5 and fallback kernel) ------------

__device__ __forceinline__ void agg_node(const unsigned short* __restrict__ xb,
                                         const int* __restrict__ csr_src,
                                         const int* __restrict__ offsets,
                                         const int* __restrict__ degree,
                                         const float* __restrict__ logsum,
                                         unsigned short* __restrict__ Zhi,
                                         float* __restrict__ ampv,
                                         float* __restrict__ attv,
                                         int N, int node, int lane) {
    int h = lane >> 5;
    int c4 = lane & 31;
    long zbase = (long)node * KDIM + c4 * 4;
    if (node >= N) {   // pad rows: zero so GEMM reads are harmless
        if (h == 0) {
            uint2 z = make_uint2(0u, 0u);
            #pragma unroll
            for (int sec = 0; sec < 4; ++sec) *(uint2*)&Zhi[zbase + sec * 128] = z;
        }
        return;
    }
    int deg = degree[node];
    int end = offsets[node];          // post-fill end of segment
    int beg = end - deg;
    const float NEG = -3.402823466e38f;
    float4 s[4], m[4];
    #pragma unroll
    for (int u = 0; u < 4; ++u) {
        s[u] = make_float4(0.f, 0.f, 0.f, 0.f);
        m[u] = make_float4(NEG, NEG, NEG, NEG);
    }
    int i = beg;
    for (; i + 8 <= end; i += 8) {      // 4 pair-slots = 8 edges, 4 indep chains
        int idx[4];
        #pragma unroll
        for (int u = 0; u < 4; ++u) idx[u] = csr_src[i + u * 2 + h];
        uint2 raw[4];
        #pragma unroll
        for (int u = 0; u < 4; ++u) raw[u] = *(const uint2*)&xb[(long)idx[u] * IN_CH + c4 * 4];
        #pragma unroll
        for (int u = 0; u < 4; ++u) {
            float4 v = unpack4(raw[u]);
            s[u].x += v.x; s[u].y += v.y; s[u].z += v.z; s[u].w += v.w;
            m[u].x = fmaxf(m[u].x, v.x); m[u].y = fmaxf(m[u].y, v.y);
            m[u].z = fmaxf(m[u].z, v.z); m[u].w = fmaxf(m[u].w, v.w);
        }
    }
    for (; i < end; i += 2) {           // tail pairs (upper half may be inactive)
        int e = i + h;
        if (e < end) {
            float4 v = unpack4(*(const uint2*)&xb[(long)csr_src[e] * IN_CH + c4 * 4]);
            s[0].x += v.x; s[0].y += v.y; s[0].z += v.z; s[0].w += v.w;
            m[0].x = fmaxf(m[0].x, v.x); m[0].y = fmaxf(m[0].y, v.y);
            m[0].z = fmaxf(m[0].z, v.z); m[0].w = fmaxf(m[0].w, v.w);
        }
    }
    float4 sum, mx;
    sum.x = (s[0].x + s[1].x) + (s[2].x + s[3].x);
    sum.y = (s[0].y + s[1].y) + (s[2].y + s[3].y);
    sum.z = (s[0].z + s[1].z) + (s[2].z + s[3].z);
    sum.w = (s[0].w + s[1].w) + (s[2].w + s[3].w);
    mx.x = fmaxf(fmaxf(m[0].x, m[1].x), fmaxf(m[2].x, m[3].x));
    mx.y = fmaxf(fmaxf(m[0].y, m[1].y), fmaxf(m[2].y, m[3].y));
    mx.z = fmaxf(fmaxf(m[0].z, m[1].z), fmaxf(m[2].z, m[3].z));
    mx.w = fmaxf(fmaxf(m[0].w, m[1].w), fmaxf(m[2].w, m[3].w));
    // cross-half combine
    sum.x += __shfl_xor(sum.x, 32); sum.y += __shfl_xor(sum.y, 32);
    sum.z += __shfl_xor(sum.z, 32); sum.w += __shfl_xor(sum.w, 32);
    mx.x = fmaxf(mx.x, __shfl_xor(mx.x, 32)); mx.y = fmaxf(mx.y, __shfl_xor(mx.y, 32));
    mx.z = fmaxf(mx.z, __shfl_xor(mx.z, 32)); mx.w = fmaxf(mx.w, __shfl_xor(mx.w, 32));

    float inv = 1.0f / fmaxf((float)deg, 1.0f);
    float4 mean = make_float4(sum.x * inv, sum.y * inv, sum.z * inv, sum.w * inv);
    if (deg == 0) mx = make_float4(0.f, 0.f, 0.f, 0.f);
    float4 xv = unpack4(*(const uint2*)&xb[(long)node * IN_CH + c4 * 4]);

    if (h == 0) {
        float4 secs[4] = { xv, sum, mean, mx };
        #pragma unroll
        for (int sec = 0; sec < 4; ++sec) {
            float4 v = secs[sec];
            uint2 hi;
            hi.x = (unsigned)f2bf(v.x) | ((unsigned)f2bf(v.y) << 16);
            hi.y = (unsigned)f2bf(v.z) | ((unsigned)f2bf(v.w) << 16);
            *(uint2*)&Zhi[zbase + sec * 128] = hi;
        }
    }
    if (lane == 0) {
        float ref = fmaxf(logsum[0] / (float)N, 1.0f);
        float dt = log1pf((float)deg + 1.0f);
        ampv[node] = dt / ref;
        attv[node] = ref / fmaxf(dt, 1e-6f);
    }
}

// ---------------- fused pre-pipeline: cooperative, 6 phases ------------------------
// P0 zero degree+logsum, xcast | P1 degree atomics | P2 chunk sums (part, logsum)
// P3 offsets (exclusive scan) | P4 fill csr | P5 agg. grid.sync between phases.
// All phases grid-stride -> correct for any resident block count.

__global__ __launch_bounds__(256) void fused_pre(const int* __restrict__ ei,
                                                 const float* __restrict__ x,
                                                 unsigned short* __restrict__ xb,
                                                 int* __restrict__ degree,
                                                 float* __restrict__ logsum,
                                                 int* __restrict__ part,
                                                 int* __restrict__ offsets,
                                                 int* __restrict__ csr_src,
                                                 unsigned short* __restrict__ Zhi,
                                                 float* __restrict__ ampv,
                                                 float* __restrict__ attv,
                                                 int N, int E, int total4, int Sb, int Mpad) {
    cg::grid_group grid = cg::this_grid();
    const int tid = threadIdx.x;
    const int lane = tid & 63;
    const int wv = tid >> 6;
    const int gsize = gridDim.x * 256;
    const int gt = blockIdx.x * 256 + tid;
    __shared__ int sd[4];
    __shared__ float sl[4];
    __shared__ int bsum[4];
    __shared__ int wsum[4];

    // P0: zero degree + logsum; x -> bf16 cast
    for (int i = gt; i < N; i += gsize) degree[i] = 0;
    if (gt == 0) logsum[0] = 0.f;
    for (int i = gt; i < total4; i += gsize) {
        float4 v = ((const float4*)x)[i];
        uint2 p;
        p.x = (unsigned)f2bf(v.x) | ((unsigned)f2bf(v.y) << 16);
        p.y = (unsigned)f2bf(v.z) | ((unsigned)f2bf(v.w) << 16);
        ((uint2*)xb)[i] = p;
    }
    grid.sync();

    // P1: degree atomics
    for (int e = gt; e < E; e += gsize) atomicAdd(&degree[ei[E + e]], 1);
    grid.sync();

    // P2: per-chunk (256 nodes) sums -> part[], logsum atomic
    for (int ch = blockIdx.x; ch < Sb; ch += gridDim.x) {
        __syncthreads();                       // shared reuse across chunk iterations
        int i = ch * 256 + tid;
        int d = (i < N) ? degree[i] : 0;
        float lg = (i < N) ? logf((float)d + 2.0f) : 0.f;   // == log1p(d+1)
        #pragma unroll
        for (int off = 32; off; off >>= 1) {
            d += __shfl_down(d, off);
            lg += __shfl_down(lg, off);
        }
        if (lane == 0) { sd[wv] = d; sl[wv] = lg; }
        __syncthreads();
        if (tid == 0) {
            part[ch] = (sd[0] + sd[1]) + (sd[2] + sd[3]);
            atomicAdd(&logsum[0], (sl[0] + sl[1]) + (sl[2] + sl[3]));
        }
    }
    grid.sync();

    // P3: offsets: per-chunk base = sum part[0..ch), then block-local exclusive scan
    for (int ch = blockIdx.x; ch < Sb; ch += gridDim.x) {
        __syncthreads();
        int i = ch * 256 + tid;
        int acc0 = 0;
        for (int j = tid; j < ch; j += 256) acc0 += part[j];
        #pragma unroll
        for (int off = 32; off; off >>= 1) acc0 += __shfl_down(acc0, off);
        if (lane == 0) bsum[wv] = acc0;
        __syncthreads();
        int base = (bsum[0] + bsum[1]) + (bsum[2] + bsum[3]);

        int d = (i < N) ? degree[i] : 0;
        int s = d;
        #pragma unroll
        for (int off = 1; off < 64; off <<= 1) {
            int t = __shfl_up(s, off);
            if (lane >= off) s += t;
        }
        if (lane == 63) wsum[wv] = s;
        __syncthreads();
        for (int w2 = 0; w2 < wv; ++w2) base += wsum[w2];
        if (i < N) offsets[i] = base + s - d;
        if (i == N - 1) offsets[N] = E;
    }
    grid.sync();

    // P4: fill csr (offsets[] bumped in place to segment ends)
    for (int e = gt; e < E; e += gsize) {
        int src = ei[e];
        int dst = ei[E + e];
        int pos = atomicAdd(&offsets[dst], 1);
        csr_src[pos] = src;
    }
    grid.sync();

    // P5: agg — one wave per node, grid-stride
    {
        int wid = gt >> 6;
        int nw = gsize >> 6;
        for (int node = wid; node < Mpad; node += nw)
            agg_node(xb, csr_src, offsets, degree, logsum, Zhi, ampv, attv, N, node, lane);
    }
}

// ---------------- fallback path kernels (non-cooperative, as r8) -------------------

__global__ __launch_bounds__(256) void prep_kernel(const int* __restrict__ ei,
                                                   int* __restrict__ degree,
                                                   float* __restrict__ logsum,
                                                   const float* __restrict__ x,
                                                   unsigned short* __restrict__ xb,
                                                   int E, int total4) {
    int i = blockIdx.x * 256 + threadIdx.x;
    if (i == 0) logsum[0] = 0.f;
    if (i < E) atomicAdd(&degree[ei[E + i]], 1);
    if (i < total4) {
        float4 v = ((const float4*)x)[i];
        uint2 p;
        p.x = (unsigned)f2bf(v.x) | ((unsigned)f2bf(v.y) << 16);
        p.y = (unsigned)f2bf(v.z) | ((unsigned)f2bf(v.w) << 16);
        ((uint2*)xb)[i] = p;
    }
}

__global__ __launch_bounds__(256) void scan1_kernel(const int* __restrict__ degree,
                                                    int* __restrict__ part,
                                                    float* __restrict__ logsum, int n) {
    int i = blockIdx.x * 256 + threadIdx.x;
    int d = (i < n) ? degree[i] : 0;
    float lg = (i < n) ? logf((float)d + 2.0f) : 0.f;
    #pragma unroll
    for (int off = 32; off; off >>= 1) {
        d += __shfl_down(d, off);
        lg += __shfl_down(lg, off);
    }
    __shared__ int sd[4];
    __shared__ float sl[4];
    int wv = threadIdx.x >> 6;
    if ((threadIdx.x & 63) == 0) { sd[wv] = d; sl[wv] = lg; }
    __syncthreads();
    if (threadIdx.x == 0) {
        part[blockIdx.x] = (sd[0] + sd[1]) + (sd[2] + sd[3]);
        atomicAdd(&logsum[0], (sl[0] + sl[1]) + (sl[2] + sl[3]));
    }
}

__global__ __launch_bounds__(256) void scan3_kernel(const int* __restrict__ degree,
                                                    const int* __restrict__ part,
                                                    int* __restrict__ offsets,
                                                    int n, int E, int Sb) {
    int tid = threadIdx.x;
    int i = blockIdx.x * 256 + tid;
    int b = blockIdx.x;
    int acc0 = 0;
    for (int j = tid; j < b; j += 256) acc0 += part[j];
    #pragma unroll
    for (int off = 32; off; off >>= 1) acc0 += __shfl_down(acc0, off);
    __shared__ int bsum[4];
    int lane = tid & 63, wv = tid >> 6;
    if (lane == 0) bsum[wv] = acc0;
    __syncthreads();
    int base = (bsum[0] + bsum[1]) + (bsum[2] + bsum[3]);

    int d = (i < n) ? degree[i] : 0;
    int s = d;
    #pragma unroll
    for (int off = 1; off < 64; off <<= 1) {
        int t = __shfl_up(s, off);
        if (lane >= off) s += t;
    }
    __shared__ int wsum[4];
    if (lane == 63) wsum[wv] = s;
    __syncthreads();
    for (int w2 = 0; w2 < wv; ++w2) base += wsum[w2];
    if (i < n) offsets[i] = base + s - d;
    if (i == n - 1) offsets[n] = E;
}

__global__ void fill_kernel(const int* __restrict__ ei, int* __restrict__ offsets,
                            int* __restrict__ csr_src, int E) {
    int e = blockIdx.x * blockDim.x + threadIdx.x;
    if (e < E) {
        int src = ei[e];
        int dst = ei[E + e];
        int pos = atomicAdd(&offsets[dst], 1);
        csr_src[pos] = src;
    }
}

__global__ __launch_bounds__(256) void agg_kernel(const unsigned short* __restrict__ xb,
                                                  const int* __restrict__ csr_src,
                                                  const int* __restrict__ offsets,
                                                  const int* __restrict__ degree,
                                                  const float* __restrict__ logsum,
                                                  unsigned short* __restrict__ Zhi,
                                                  float* __restrict__ ampv,
                                                  float* __restrict__ attv,
                                                  int N, int Mpad) {
    int node = (blockIdx.x * 256 + threadIdx.x) >> 6;
    int lane = threadIdx.x & 63;
    if (node >= Mpad) return;
    agg_node(xb, csr_src, offsets, degree, logsum, Zhi, ampv, attv, N, node, lane);
}

// ---------------- Weight build: permuted row-major W^T, bf16 hi/lo -----------------

__global__ void wbuild_kernel(const float* __restrict__ Wmsg, const float* __restrict__ Wroot,
                              unsigned short* __restrict__ Whi, unsigned short* __restrict__ Wlo) {
    int idx = blockIdx.x * 256 + threadIdx.x;
    if (idx >= NGEMM * KDIM) return;
    int jp = idx >> 9;       // 0..383
    int k = idx & 511;
    int cg2 = jp / 96;
    int rem = jp - cg2 * 96;
    int s16 = rem >> 4;
    int r16 = rem & 15;
    int wn2 = s16 / 3;
    int sec = s16 - wn2 * 3;
    int ocol = cg2 * 32 + wn2 * 16 + r16;
    float v;
    if (k < 128) {
        v = (sec == 0) ? Wroot[ocol * 128 + k] : 0.f;
    } else {
        int a = (k - 128) >> 7;
        int c = (k - 128) & 127;
        v = Wmsg[ocol * 1152 + (a * 3 + sec) * 128 + c];
    }
    unsigned short h = f2bf(v);
    Whi[idx] = h;
    Wlo[idx] = f2bf(v - bf2f(h));
}

// ---------------- MFMA GEMM: GBM=448, single-round grid (r8, unchanged) ------------

__global__ __launch_bounds__(1024, 4) void gemm_pipe(const unsigned short* __restrict__ Zhi,
                                                     const unsigned short* __restrict__ Whi,
                                                     const unsigned short* __restrict__ Wlo,
                                                     const float* __restrict__ ampv,
                                                     const float* __restrict__ attv,
                                                     const float* __restrict__ bmsg,
                                                     const float* __restrict__ broot,
                                                     float* __restrict__ out, int M) {
    extern __shared__ char smem[];
    unsigned short* lds = (unsigned short*)smem;
    const int tid = threadIdx.x;
    const int w = tid >> 6;                 // 0..15
    const int lane = tid & 63;
    const int r16 = lane & 15, q = lane >> 4;
    const int wm = w >> 2, wn = w & 3;
    const int row0 = blockIdx.x * GBMP;
    const int cg2 = blockIdx.y;             // 0..1
    const bool four = (w >= 12);

    const int cbase = four ? (36 + 4 * (w - 12)) : (3 * w);
    const unsigned short* sP[4];
    int dd[4];
    #pragma unroll
    for (int j = 0; j < 4; ++j) {
        int c = cbase + ((four || j < 3) ? j : 0);
        if (c < 28) {
            sP[j] = Zhi + (long)(row0 + c * 16 + r16) * KDIM + q * 8;
        } else {
            int b = c - 28;
            const unsigned short* Wb = (b < 12) ? Whi : Wlo;
            int rr = (b < 12) ? b * 16 : (b - 12) * 16;
            sP[j] = Wb + (long)(cg2 * GBN + rr + r16) * KDIM + q * 8;
        }
        dd[j] = c * 1024 + lane * 16;
    }

    #pragma unroll
    for (int p = 0; p < 2; ++p) {
        char* b = smem + p * SLOT_B;
        gl2lds16(sP[0], b + dd[0]); gl2lds16(sP[1], b + dd[1]); gl2lds16(sP[2], b + dd[2]);
        if (four) gl2lds16(sP[3], b + dd[3]);
        #pragma unroll
        for (int j = 0; j < 4; ++j) sP[j] += 32;
    }

    if (four) __builtin_amdgcn_s_waitcnt(0x0F74);   // vmcnt(4)
    else      __builtin_amdgcn_s_waitcnt(0x0F73);   // vmcnt(3)
    __builtin_amdgcn_s_barrier();
    __builtin_amdgcn_sched_barrier(0);

    f32x4 acc[7][3] = {};
    const int jtb = (wn >> 1) * 6 + (wn & 1) * 3;

    #pragma unroll 1
    for (int it = 0; it < 16; ++it) {
        const int s = it % 3;
        if (it + 2 < 16) {
            char* b = smem + ((it + 2) % 3) * SLOT_B;
            gl2lds16(sP[0], b + dd[0]); gl2lds16(sP[1], b + dd[1]); gl2lds16(sP[2], b + dd[2]);
            if (four) gl2lds16(sP[3], b + dd[3]);
            #pragma unroll
            for (int j = 0; j < 4; ++j) sP[j] += 32;
        }
        const unsigned short* L = lds + s * SLOT_US;

        bfrag bh[3], bl[3];
        #pragma unroll
        for (int nt = 0; nt < 3; ++nt) {
            int chb = (jtb + nt) * 512 + lane * 8;
            bh[nt] = *(const bfrag*)&L[14336 + chb];
            bl[nt] = *(const bfrag*)&L[20480 + chb];
        }
        #pragma unroll
        for (int mt = 0; mt < 7; ++mt) {
            bfrag ah = *(const bfrag*)&L[((wm * 7 + mt) * 64 + lane) * 8];
            #pragma unroll
            for (int nt = 0; nt < 3; ++nt) {
                acc[mt][nt] = __builtin_amdgcn_mfma_f32_16x16x32_bf16(ah, bh[nt], acc[mt][nt], 0, 0, 0);
                acc[mt][nt] = __builtin_amdgcn_mfma_f32_16x16x32_bf16(ah, bl[nt], acc[mt][nt], 0, 0, 0);
            }
        }

        if (it < 14) {
            if (four) __builtin_amdgcn_s_waitcnt(0x0F74);
            else      __builtin_amdgcn_s_waitcnt(0x0F73);
        } else if (it == 14) {
            __builtin_amdgcn_s_waitcnt(0x0F70);
        }
        if (it < 15) {
            __builtin_amdgcn_s_barrier();
            __builtin_amdgcn_sched_barrier(0);
        }
    }

    const int col = (cg2 * 2 + (wn >> 1)) * 32 + (wn & 1) * 16 + r16;
    const float bias = bmsg[col] + broot[col];
    #pragma unroll
    for (int mt = 0; mt < 7; ++mt) {
        #pragma unroll
        for (int r = 0; r < 4; ++r) {
            int row = row0 + wm * 112 + mt * 16 + q * 4 + r;
            if (row < M) {
                float v = acc[mt][0][r]
                        + ampv[row] * acc[mt][1][r]
                        + attv[row] * acc[mt][2][r] + bias;
                out[(long)row * OUT_CH + col] = v;
            }
        }
    }
}

// ---------------- fallback: single-buffer gemm (static 40 KB) ----------------------

__global__ __launch_bounds__(1024, 4) void gemm_sb(const unsigned short* __restrict__ Zhi,
                                                   const unsigned short* __restrict__ Whi,
                                                   const unsigned short* __restrict__ Wlo,
                                                   const float* __restrict__ ampv,
                                                   const float* __restrict__ attv,
                                                   const float* __restrict__ bmsg,
                                                   const float* __restrict__ broot,
                                                   float* __restrict__ out, int M) {
    __shared__ unsigned short lds[SB_SLOT_US];   // 40 KB
    const int tid = threadIdx.x;
    const int w = tid >> 6;
    const int lane = tid & 63;
    const int r16 = lane & 15, q = lane >> 4;
    const int wm = w >> 2, wn = w & 3;
    const int row0 = blockIdx.x * GBM;
    const int cg2 = blockIdx.y;

    const unsigned short* sAh = Zhi + (long)(row0 + w * 16 + r16) * KDIM + q * 8;
    const unsigned short* sB2 = (w < 12)
        ? Whi + (long)(cg2 * GBN + w * 16 + r16) * KDIM + q * 8
        : Wlo + (long)(cg2 * GBN + (w - 12) * 16 + r16) * KDIM + q * 8;
    const unsigned short* sB3 = Wlo + (long)(cg2 * GBN + (4 + w) * 16 + r16) * KDIM + q * 8;
    char* ldsb = (char*)lds;
    const int d0 = tid * 16, d2 = (1024 + tid) * 16, d3 = (2048 + tid) * 16;

    f32x4 acc[4][3] = {};
    const int jtb = (wn >> 1) * 6 + (wn & 1) * 3;

    #pragma unroll 1
    for (int it = 0; it < 16; ++it) {
        if (it) __syncthreads();
        gl2lds16(sAh, ldsb + d0); gl2lds16(sB2, ldsb + d2); if (w < 8) gl2lds16(sB3, ldsb + d3);
        sAh += 32; sB2 += 32; sB3 += 32;
        __syncthreads();

        bfrag bh[3], bl[3];
        #pragma unroll
        for (int nt = 0; nt < 3; ++nt) {
            int chb = (jtb + nt) * 512 + lane * 8;
            bh[nt] = *(const bfrag*)&lds[8192 + chb];
            bl[nt] = *(const bfrag*)&lds[14336 + chb];
        }
        #pragma unroll
        for (int mt = 0; mt < 4; ++mt) {
            bfrag ah = *(const bfrag*)&lds[((wm * 4 + mt) * 64 + lane) * 8];
            #pragma unroll
            for (int nt = 0; nt < 3; ++nt) {
                acc[mt][nt] = __builtin_amdgcn_mfma_f32_16x16x32_bf16(ah, bh[nt], acc[mt][nt], 0, 0, 0);
                acc[mt][nt] = __builtin_amdgcn_mfma_f32_16x16x32_bf16(ah, bl[nt], acc[mt][nt], 0, 0, 0);
            }
        }
    }

    const int col = (cg2 * 2 + (wn >> 1)) * 32 + (wn & 1) * 16 + r16;
    const float bias = bmsg[col] + broot[col];
    #pragma unroll
    for (int mt = 0; mt < 4; ++mt) {
        #pragma unroll
        for (int r = 0; r < 4; ++r) {
            int row = row0 + wm * 64 + mt * 16 + q * 4 + r;
            if (row < M) {
                float v = acc[mt][0][r]
                        + ampv[row] * acc[mt][1][r]
                        + attv[row] * acc[mt][2][r] + bias;
                out[(long)row * OUT_CH + col] = v;
            }
        }
    }
}

// ---------------- Launch ----------------

extern "C" void kernel_launch(void* const* d_in, const int* in_sizes, int n_in,
                              void* d_out, int out_size, void* d_ws, size_t ws_size,
                              hipStream_t stream) {
    const float* x     = (const float*)d_in[0];
    const int*   ei    = (const int*)d_in[1];
    const float* Wmsg  = (const float*)d_in[2];
    const float* bmsg  = (const float*)d_in[3];
    const float* Wroot = (const float*)d_in[4];
    const float* broot = (const float*)d_in[5];
    float* out = (float*)d_out;

    int N = in_sizes[0] / IN_CH;           // 50000
    int E = in_sizes[1] / 2;               // 600000
    int Mpad = 50176;                      // = 112*448 = 196*256
    if (N > Mpad) Mpad = ((N + 447) / 448) * 448;
    int MbP = (Mpad + GBMP - 1) / GBMP;    // 112 pipe blocks
    int MbS = (Mpad + GBM - 1) / GBM;      // fallback blocks
    int Sb = (N + 255) / 256;              // scan chunks (196)
    int total4 = N * IN_CH / 4;

    char* ws = (char*)d_ws;
    size_t off = 0;
    auto alloc = [&](size_t bytes) -> void* {
        void* p = ws + off;
        off = (off + bytes + 255) & ~(size_t)255;
        return p;
    };
    size_t MpadA = (size_t)MbP * GBMP;
    if ((size_t)MbS * GBM > MpadA) MpadA = (size_t)MbS * GBM;
    int* degree  = (int*)alloc((size_t)N * 4);
    int* offsets = (int*)alloc((size_t)(N + 1) * 4);
    float* logsum = (float*)alloc(4);
    int* part    = (int*)alloc((size_t)Sb * 4);
    int* csr_src = (int*)alloc((size_t)E * 4);
    unsigned short* Whi = (unsigned short*)alloc((size_t)NGEMM * KDIM * 2);
    unsigned short* Wlo = (unsigned short*)alloc((size_t)NGEMM * KDIM * 2);
    unsigned short* Zhi = (unsigned short*)alloc(MpadA * KDIM * 2);
    unsigned short* xb  = (unsigned short*)alloc(MpadA * IN_CH * 2);
    float* ampv = (float*)alloc((size_t)N * 4);
    float* attv = (float*)alloc((size_t)N * 4);
    int MpadZ = (int)MpadA;

    // host-side capability queries (capture-safe, no stream ops)
    int dev = 0;
    bool haveDev = (hipGetDevice(&dev) == hipSuccess);
    int coop = 0, numCU = 256;
    if (haveDev) {
        hipDeviceGetAttribute(&coop, hipDeviceAttributeCooperativeLaunch, dev);
        hipDeviceGetAttribute(&numCU, hipDeviceAttributeMultiprocessorCount, dev);
    }
    bool pipe = false;
    if (haveDev) {
        int optin = 0;
        if (hipDeviceGetAttribute(&optin, hipDeviceAttributeSharedMemPerBlockOptin, dev) == hipSuccess
            && optin >= (int)PIPE_LDS_BYTES) {
            pipe = (hipFuncSetAttribute((const void*)gemm_pipe,
                                        hipFuncAttributeMaxDynamicSharedMemorySize,
                                        PIPE_LDS_BYTES) == hipSuccess);
        }
    }

    bool usedCoop = false;
    if (coop) {
        int occ = 0;
        if (hipOccupancyMaxActiveBlocksPerMultiprocessor(&occ, (const void*)fused_pre, 256, 0)
                == hipSuccess && occ > 0) {
            int blocks = occ * numCU;
            if (blocks > 2048) blocks = 2048;
            void* args[] = { (void*)&ei, (void*)&x, (void*)&xb, (void*)&degree,
                             (void*)&logsum, (void*)&part, (void*)&offsets, (void*)&csr_src,
                             (void*)&Zhi, (void*)&ampv, (void*)&attv,
                             (void*)&N, (void*)&E, (void*)&total4, (void*)&Sb, (void*)&MpadZ };
            usedCoop = (hipLaunchCooperativeKernel((const void*)fused_pre, dim3(blocks), dim3(256),
                                                   args, 0, stream) == hipSuccess);
        }
    }
    if (!usedCoop) {
        hipMemsetAsync(degree, 0, (size_t)N * 4, stream);
        int prepg = (max(E, total4) + 255) / 256;
        prep_kernel<<<prepg, 256, 0, stream>>>(ei, degree, logsum, x, xb, E, total4);
        scan1_kernel<<<Sb, 256, 0, stream>>>(degree, part, logsum, N);
        scan3_kernel<<<Sb, 256, 0, stream>>>(degree, part, offsets, N, E, Sb);
        fill_kernel<<<(E + 255) / 256, 256, 0, stream>>>(ei, offsets, csr_src, E);
        agg_kernel<<<(MpadZ * 64 + 255) / 256, 256, 0, stream>>>(xb, csr_src, offsets, degree,
                                                                 logsum, Zhi, ampv, attv, N, MpadZ);
    }
    wbuild_kernel<<<(NGEMM * KDIM + 255) / 256, 256, 0, stream>>>(Wmsg, Wroot, Whi, Wlo);

    if (pipe) {
        dim3 ggrid(MbP, 2);
        gemm_pipe<<<ggrid, 1024, PIPE_LDS_BYTES, stream>>>(Zhi, Whi, Wlo, ampv, attv,
                                                           bmsg, broot, out, N);
    } else {
        dim3 ggrid(MbS, 2);
        gemm_sb<<<ggrid, 1024, 0, stream>>>(Zhi, Whi, Wlo, ampv, attv,
                                            bmsg, broot, out, N);
    }
}

// Round 10
// 250.965 us; speedup vs baseline: 2.7179x; 2.7179x over previous
//
#include <hip/hip_runtime.h>
#include <cmath>

#define IN_CH 128
#define OUT_CH 128
#define KDIM 512           // Z row: x(128) | sum(128) | mean(128) | max(128)
#define NGEMM 384          // W^T rows: permuted (colgroup, wavehalf, section, ocol16)
#define GBM 256            // fallback gemm rows per block
#define GBMP 448           // pipe gemm rows per block (single-round packing)
#define GBN 192            // gemm cols (W^T rows) per block
#define SLOT_B 53248       // pipe slot bytes: A 28K | Bhi 12K | Blo 12K
#define SLOT_US 26624
#define SB_SLOT_US 20480   // fallback single-buffer slot
#define PIPE_LDS_BYTES (3 * SLOT_B)   // D=3 ring = 159744 B <= 160 KiB

typedef __attribute__((ext_vector_type(8))) short bfrag;   // 8 bf16 in 4 VGPRs
typedef __attribute__((ext_vector_type(4))) float f32x4;

// float -> bf16 round-to-nearest-even (bit pattern)
__device__ __forceinline__ unsigned short f2bf(float f) {
    unsigned int u = __float_as_uint(f);
    return (unsigned short)((u + 0x7FFFu + ((u >> 16) & 1u)) >> 16);
}
__device__ __forceinline__ float bf2f(unsigned short h) {
    return __uint_as_float(((unsigned int)h) << 16);
}
__device__ __forceinline__ float4 unpack4(uint2 u) {
    float4 r;
    r.x = __uint_as_float(u.x << 16);
    r.y = __uint_as_float(u.x & 0xFFFF0000u);
    r.z = __uint_as_float(u.y << 16);
    r.w = __uint_as_float(u.y & 0xFFFF0000u);
    return r;
}

// async 16B global->LDS (wave-level; LDS side is lane-linear base+lane*16)
__device__ __forceinline__ void gl2lds16(const void* g, void* l) {
    __builtin_amdgcn_global_load_lds(
        (const __attribute__((address_space(1))) unsigned int*)g,
        (__attribute__((address_space(3))) unsigned int*)l, 16, 0, 0);
}

// ---------------- init: zero degree+logsum + weight build (independent work) -------
// wbuild: permuted row-major W^T, bf16 hi/lo split.

__global__ __launch_bounds__(256) void init_kernel(int* __restrict__ degree,
                                                   float* __restrict__ logsum,
                                                   const float* __restrict__ Wmsg,
                                                   const float* __restrict__ Wroot,
                                                   unsigned short* __restrict__ Whi,
                                                   unsigned short* __restrict__ Wlo,
                                                   int N) {
    int idx = blockIdx.x * 256 + threadIdx.x;
    if (idx == 0) logsum[0] = 0.f;
    if (idx < N) degree[idx] = 0;
    if (idx < NGEMM * KDIM) {
        int jp = idx >> 9;       // 0..383
        int k = idx & 511;
        int cg2 = jp / 96;
        int rem = jp - cg2 * 96;
        int s16 = rem >> 4;
        int r16 = rem & 15;
        int wn2 = s16 / 3;
        int sec = s16 - wn2 * 3;
        int ocol = cg2 * 32 + wn2 * 16 + r16;
        float v;
        if (k < 128) {
            v = (sec == 0) ? Wroot[ocol * 128 + k] : 0.f;
        } else {
            int a = (k - 128) >> 7;
            int c = (k - 128) & 127;
            v = Wmsg[ocol * 1152 + (a * 3 + sec) * 128 + c];
        }
        unsigned short h = f2bf(v);
        Whi[idx] = h;
        Wlo[idx] = f2bf(v - bf2f(h));
    }
}

// ---------------- prep: degree atomics + x->bf16 cast ------------------------------

__global__ __launch_bounds__(256) void prep_kernel(const int* __restrict__ ei,
                                                   int* __restrict__ degree,
                                                   const float* __restrict__ x,
                                                   unsigned short* __restrict__ xb,
                                                   int E, int total4) {
    int i = blockIdx.x * 256 + threadIdx.x;
    if (i < E) atomicAdd(&degree[ei[E + i]], 1);
    if (i < total4) {
        float4 v = ((const float4*)x)[i];
        uint2 p;
        p.x = (unsigned)f2bf(v.x) | ((unsigned)f2bf(v.y) << 16);
        p.y = (unsigned)f2bf(v.z) | ((unsigned)f2bf(v.w) << 16);
        ((uint2*)xb)[i] = p;
    }
}

// ---------------- offsets: exclusive scan via direct degree-prefix sum + logsum ----
// part[] eliminated: block ch sums degree[0..ch*256) directly (degree = 200 KB,
// L2-resident; total redundant reads ~20 MB, ~free). Also accumulates logsum.

__global__ __launch_bounds__(256) void offsets_kernel(const int* __restrict__ degree,
                                                      int* __restrict__ offsets,
                                                      float* __restrict__ logsum,
                                                      int n, int E) {
    int tid = threadIdx.x;
    int ch = blockIdx.x;
    int i = ch * 256 + tid;
    int lane = tid & 63, wv = tid >> 6;

    // base = sum degree[0 .. ch*256), coalesced tid-stride
    int lim = ch * 256;
    int acc0 = 0;
    for (int j = tid; j < lim; j += 256) acc0 += degree[j];
    #pragma unroll
    for (int off = 32; off; off >>= 1) acc0 += __shfl_down(acc0, off);
    __shared__ int bsum[4];
    if (lane == 0) bsum[wv] = acc0;
    __syncthreads();
    int base = (bsum[0] + bsum[1]) + (bsum[2] + bsum[3]);

    int d = (i < n) ? degree[i] : 0;
    float lg = (i < n) ? logf((float)d + 2.0f) : 0.f;   // == log1p(d+1)
    // logsum partial (order-free atomic accumulate)
    float lgs = lg;
    #pragma unroll
    for (int off = 32; off; off >>= 1) lgs += __shfl_down(lgs, off);
    __shared__ float sl[4];
    if (lane == 0) sl[wv] = lgs;
    // block-local exclusive scan of degrees
    int s = d;
    #pragma unroll
    for (int off = 1; off < 64; off <<= 1) {
        int t = __shfl_up(s, off);
        if (lane >= off) s += t;
    }
    __shared__ int wsum[4];
    if (lane == 63) wsum[wv] = s;
    __syncthreads();
    if (tid == 0) atomicAdd(&logsum[0], (sl[0] + sl[1]) + (sl[2] + sl[3]));
    for (int w2 = 0; w2 < wv; ++w2) base += wsum[w2];
    if (i < n) offsets[i] = base + s - d;             // exclusive prefix
    if (i == n - 1) offsets[n] = E;                   // Σ degree == E
}

// fill bumps offsets[] in place; afterwards offsets[v] == end of v's segment.
__global__ void fill_kernel(const int* __restrict__ ei, int* __restrict__ offsets,
                            int* __restrict__ csr_src, int E) {
    int e = blockIdx.x * blockDim.x + threadIdx.x;
    if (e < E) {
        int src = ei[e];
        int dst = ei[E + e];
        int pos = atomicAdd(&offsets[dst], 1);
        csr_src[pos] = src;
    }
}

// ---------------- Aggregation: one WAVE per node, bf16 edge-pair gathers ---------

__device__ __forceinline__ void agg_node(const unsigned short* __restrict__ xb,
                                         const int* __restrict__ csr_src,
                                         const int* __restrict__ offsets,
                                         const int* __restrict__ degree,
                                         const float* __restrict__ logsum,
                                         unsigned short* __restrict__ Zhi,
                                         float* __restrict__ ampv,
                                         float* __restrict__ attv,
                                         int N, int node, int lane) {
    int h = lane >> 5;
    int c4 = lane & 31;
    long zbase = (long)node * KDIM + c4 * 4;
    if (node >= N) {   // pad rows: zero so GEMM reads are harmless
        if (h == 0) {
            uint2 z = make_uint2(0u, 0u);
            #pragma unroll
            for (int sec = 0; sec < 4; ++sec) *(uint2*)&Zhi[zbase + sec * 128] = z;
        }
        return;
    }
    int deg = degree[node];
    int end = offsets[node];          // post-fill end of segment
    int beg = end - deg;
    const float NEG = -3.402823466e38f;
    float4 s[4], m[4];
    #pragma unroll
    for (int u = 0; u < 4; ++u) {
        s[u] = make_float4(0.f, 0.f, 0.f, 0.f);
        m[u] = make_float4(NEG, NEG, NEG, NEG);
    }
    int i = beg;
    for (; i + 8 <= end; i += 8) {      // 4 pair-slots = 8 edges, 4 indep chains
        int idx[4];
        #pragma unroll
        for (int u = 0; u < 4; ++u) idx[u] = csr_src[i + u * 2 + h];
        uint2 raw[4];
        #pragma unroll
        for (int u = 0; u < 4; ++u) raw[u] = *(const uint2*)&xb[(long)idx[u] * IN_CH + c4 * 4];
        #pragma unroll
        for (int u = 0; u < 4; ++u) {
            float4 v = unpack4(raw[u]);
            s[u].x += v.x; s[u].y += v.y; s[u].z += v.z; s[u].w += v.w;
            m[u].x = fmaxf(m[u].x, v.x); m[u].y = fmaxf(m[u].y, v.y);
            m[u].z = fmaxf(m[u].z, v.z); m[u].w = fmaxf(m[u].w, v.w);
        }
    }
    for (; i < end; i += 2) {           // tail pairs (upper half may be inactive)
        int e = i + h;
        if (e < end) {
            float4 v = unpack4(*(const uint2*)&xb[(long)csr_src[e] * IN_CH + c4 * 4]);
            s[0].x += v.x; s[0].y += v.y; s[0].z += v.z; s[0].w += v.w;
            m[0].x = fmaxf(m[0].x, v.x); m[0].y = fmaxf(m[0].y, v.y);
            m[0].z = fmaxf(m[0].z, v.z); m[0].w = fmaxf(m[0].w, v.w);
        }
    }
    float4 sum, mx;
    sum.x = (s[0].x + s[1].x) + (s[2].x + s[3].x);
    sum.y = (s[0].y + s[1].y) + (s[2].y + s[3].y);
    sum.z = (s[0].z + s[1].z) + (s[2].z + s[3].z);
    sum.w = (s[0].w + s[1].w) + (s[2].w + s[3].w);
    mx.x = fmaxf(fmaxf(m[0].x, m[1].x), fmaxf(m[2].x, m[3].x));
    mx.y = fmaxf(fmaxf(m[0].y, m[1].y), fmaxf(m[2].y, m[3].y));
    mx.z = fmaxf(fmaxf(m[0].z, m[1].z), fmaxf(m[2].z, m[3].z));
    mx.w = fmaxf(fmaxf(m[0].w, m[1].w), fmaxf(m[2].w, m[3].w));
    // cross-half combine
    sum.x += __shfl_xor(sum.x, 32); sum.y += __shfl_xor(sum.y, 32);
    sum.z += __shfl_xor(sum.z, 32); sum.w += __shfl_xor(sum.w, 32);
    mx.x = fmaxf(mx.x, __shfl_xor(mx.x, 32)); mx.y = fmaxf(mx.y, __shfl_xor(mx.y, 32));
    mx.z = fmaxf(mx.z, __shfl_xor(mx.z, 32)); mx.w = fmaxf(mx.w, __shfl_xor(mx.w, 32));

    float inv = 1.0f / fmaxf((float)deg, 1.0f);
    float4 mean = make_float4(sum.x * inv, sum.y * inv, sum.z * inv, sum.w * inv);
    if (deg == 0) mx = make_float4(0.f, 0.f, 0.f, 0.f);
    float4 xv = unpack4(*(const uint2*)&xb[(long)node * IN_CH + c4 * 4]);

    if (h == 0) {
        float4 secs[4] = { xv, sum, mean, mx };
        #pragma unroll
        for (int sec = 0; sec < 4; ++sec) {
            float4 v = secs[sec];
            uint2 hi;
            hi.x = (unsigned)f2bf(v.x) | ((unsigned)f2bf(v.y) << 16);
            hi.y = (unsigned)f2bf(v.z) | ((unsigned)f2bf(v.w) << 16);
            *(uint2*)&Zhi[zbase + sec * 128] = hi;
        }
    }
    if (lane == 0) {
        float ref = fmaxf(logsum[0] / (float)N, 1.0f);
        float dt = log1pf((float)deg + 1.0f);
        ampv[node] = dt / ref;
        attv[node] = ref / fmaxf(dt, 1e-6f);
    }
}

__global__ __launch_bounds__(256) void agg_kernel(const unsigned short* __restrict__ xb,
                                                  const int* __restrict__ csr_src,
                                                  const int* __restrict__ offsets,
                                                  const int* __restrict__ degree,
                                                  const float* __restrict__ logsum,
                                                  unsigned short* __restrict__ Zhi,
                                                  float* __restrict__ ampv,
                                                  float* __restrict__ attv,
                                                  int N, int Mpad) {
    int node = (blockIdx.x * 256 + threadIdx.x) >> 6;
    int lane = threadIdx.x & 63;
    if (node >= Mpad) return;
    agg_node(xb, csr_src, offsets, degree, logsum, Zhi, ampv, attv, N, node, lane);
}

// ---------------- MFMA GEMM: GBM=448, single-round grid (r8, unchanged) ------------
// 112x2 = 224 blocks <= 256 CUs -> one round. Slot: A 28K | B 24K; D=3 = 159744 B.
// Staging: 52 chunks/stage; waves 0-11 carry 3 (L=3), waves 12-15 carry 4 (L=4).
// Schedule: fire stage it+2, counted vmcnt(L) (window 2), raw barrier.

__global__ __launch_bounds__(1024, 4) void gemm_pipe(const unsigned short* __restrict__ Zhi,
                                                     const unsigned short* __restrict__ Whi,
                                                     const unsigned short* __restrict__ Wlo,
                                                     const float* __restrict__ ampv,
                                                     const float* __restrict__ attv,
                                                     const float* __restrict__ bmsg,
                                                     const float* __restrict__ broot,
                                                     float* __restrict__ out, int M) {
    extern __shared__ char smem[];
    unsigned short* lds = (unsigned short*)smem;
    const int tid = threadIdx.x;
    const int w = tid >> 6;                 // 0..15
    const int lane = tid & 63;
    const int r16 = lane & 15, q = lane >> 4;
    const int wm = w >> 2, wn = w & 3;
    const int row0 = blockIdx.x * GBMP;
    const int cg2 = blockIdx.y;             // 0..1
    const bool four = (w >= 12);

    const int cbase = four ? (36 + 4 * (w - 12)) : (3 * w);
    const unsigned short* sP[4];
    int dd[4];
    #pragma unroll
    for (int j = 0; j < 4; ++j) {
        int c = cbase + ((four || j < 3) ? j : 0);
        if (c < 28) {
            sP[j] = Zhi + (long)(row0 + c * 16 + r16) * KDIM + q * 8;
        } else {
            int b = c - 28;
            const unsigned short* Wb = (b < 12) ? Whi : Wlo;
            int rr = (b < 12) ? b * 16 : (b - 12) * 16;
            sP[j] = Wb + (long)(cg2 * GBN + rr + r16) * KDIM + q * 8;
        }
        dd[j] = c * 1024 + lane * 16;
    }

    #pragma unroll
    for (int p = 0; p < 2; ++p) {
        char* b = smem + p * SLOT_B;
        gl2lds16(sP[0], b + dd[0]); gl2lds16(sP[1], b + dd[1]); gl2lds16(sP[2], b + dd[2]);
        if (four) gl2lds16(sP[3], b + dd[3]);
        #pragma unroll
        for (int j = 0; j < 4; ++j) sP[j] += 32;
    }

    if (four) __builtin_amdgcn_s_waitcnt(0x0F74);   // vmcnt(4)
    else      __builtin_amdgcn_s_waitcnt(0x0F73);   // vmcnt(3)
    __builtin_amdgcn_s_barrier();
    __builtin_amdgcn_sched_barrier(0);

    f32x4 acc[7][3] = {};
    const int jtb = (wn >> 1) * 6 + (wn & 1) * 3;

    #pragma unroll 1
    for (int it = 0; it < 16; ++it) {
        const int s = it % 3;
        if (it + 2 < 16) {
            char* b = smem + ((it + 2) % 3) * SLOT_B;
            gl2lds16(sP[0], b + dd[0]); gl2lds16(sP[1], b + dd[1]); gl2lds16(sP[2], b + dd[2]);
            if (four) gl2lds16(sP[3], b + dd[3]);
            #pragma unroll
            for (int j = 0; j < 4; ++j) sP[j] += 32;
        }
        const unsigned short* L = lds + s * SLOT_US;

        bfrag bh[3], bl[3];
        #pragma unroll
        for (int nt = 0; nt < 3; ++nt) {
            int chb = (jtb + nt) * 512 + lane * 8;
            bh[nt] = *(const bfrag*)&L[14336 + chb];
            bl[nt] = *(const bfrag*)&L[20480 + chb];
        }
        #pragma unroll
        for (int mt = 0; mt < 7; ++mt) {
            bfrag ah = *(const bfrag*)&L[((wm * 7 + mt) * 64 + lane) * 8];
            #pragma unroll
            for (int nt = 0; nt < 3; ++nt) {
                acc[mt][nt] = __builtin_amdgcn_mfma_f32_16x16x32_bf16(ah, bh[nt], acc[mt][nt], 0, 0, 0);
                acc[mt][nt] = __builtin_amdgcn_mfma_f32_16x16x32_bf16(ah, bl[nt], acc[mt][nt], 0, 0, 0);
            }
        }

        if (it < 14) {
            if (four) __builtin_amdgcn_s_waitcnt(0x0F74);
            else      __builtin_amdgcn_s_waitcnt(0x0F73);
        } else if (it == 14) {
            __builtin_amdgcn_s_waitcnt(0x0F70);
        }
        if (it < 15) {
            __builtin_amdgcn_s_barrier();
            __builtin_amdgcn_sched_barrier(0);
        }
    }

    // fused epilogue: C/D layout col=lane&15, row=q*4+r (verified m89/m91)
    const int col = (cg2 * 2 + (wn >> 1)) * 32 + (wn & 1) * 16 + r16;
    const float bias = bmsg[col] + broot[col];
    #pragma unroll
    for (int mt = 0; mt < 7; ++mt) {
        #pragma unroll
        for (int r = 0; r < 4; ++r) {
            int row = row0 + wm * 112 + mt * 16 + q * 4 + r;
            if (row < M) {
                float v = acc[mt][0][r]
                        + ampv[row] * acc[mt][1][r]
                        + attv[row] * acc[mt][2][r] + bias;
                out[(long)row * OUT_CH + col] = v;
            }
        }
    }
}

// ---------------- fallback: single-buffer gemm (static 40 KB) ----------------------

__global__ __launch_bounds__(1024, 4) void gemm_sb(const unsigned short* __restrict__ Zhi,
                                                   const unsigned short* __restrict__ Whi,
                                                   const unsigned short* __restrict__ Wlo,
                                                   const float* __restrict__ ampv,
                                                   const float* __restrict__ attv,
                                                   const float* __restrict__ bmsg,
                                                   const float* __restrict__ broot,
                                                   float* __restrict__ out, int M) {
    __shared__ unsigned short lds[SB_SLOT_US];   // 40 KB
    const int tid = threadIdx.x;
    const int w = tid >> 6;
    const int lane = tid & 63;
    const int r16 = lane & 15, q = lane >> 4;
    const int wm = w >> 2, wn = w & 3;
    const int row0 = blockIdx.x * GBM;
    const int cg2 = blockIdx.y;

    const unsigned short* sAh = Zhi + (long)(row0 + w * 16 + r16) * KDIM + q * 8;
    const unsigned short* sB2 = (w < 12)
        ? Whi + (long)(cg2 * GBN + w * 16 + r16) * KDIM + q * 8
        : Wlo + (long)(cg2 * GBN + (w - 12) * 16 + r16) * KDIM + q * 8;
    const unsigned short* sB3 = Wlo + (long)(cg2 * GBN + (4 + w) * 16 + r16) * KDIM + q * 8;
    char* ldsb = (char*)lds;
    const int d0 = tid * 16, d2 = (1024 + tid) * 16, d3 = (2048 + tid) * 16;

    f32x4 acc[4][3] = {};
    const int jtb = (wn >> 1) * 6 + (wn & 1) * 3;

    #pragma unroll 1
    for (int it = 0; it < 16; ++it) {
        if (it) __syncthreads();
        gl2lds16(sAh, ldsb + d0); gl2lds16(sB2, ldsb + d2); if (w < 8) gl2lds16(sB3, ldsb + d3);
        sAh += 32; sB2 += 32; sB3 += 32;
        __syncthreads();

        bfrag bh[3], bl[3];
        #pragma unroll
        for (int nt = 0; nt < 3; ++nt) {
            int chb = (jtb + nt) * 512 + lane * 8;
            bh[nt] = *(const bfrag*)&lds[8192 + chb];
            bl[nt] = *(const bfrag*)&lds[14336 + chb];
        }
        #pragma unroll
        for (int mt = 0; mt < 4; ++mt) {
            bfrag ah = *(const bfrag*)&lds[((wm * 4 + mt) * 64 + lane) * 8];
            #pragma unroll
            for (int nt = 0; nt < 3; ++nt) {
                acc[mt][nt] = __builtin_amdgcn_mfma_f32_16x16x32_bf16(ah, bh[nt], acc[mt][nt], 0, 0, 0);
                acc[mt][nt] = __builtin_amdgcn_mfma_f32_16x16x32_bf16(ah, bl[nt], acc[mt][nt], 0, 0, 0);
            }
        }
    }

    const int col = (cg2 * 2 + (wn >> 1)) * 32 + (wn & 1) * 16 + r16;
    const float bias = bmsg[col] + broot[col];
    #pragma unroll
    for (int mt = 0; mt < 4; ++mt) {
        #pragma unroll
        for (int r = 0; r < 4; ++r) {
            int row = row0 + wm * 64 + mt * 16 + q * 4 + r;
            if (row < M) {
                float v = acc[mt][0][r]
                        + ampv[row] * acc[mt][1][r]
                        + attv[row] * acc[mt][2][r] + bias;
                out[(long)row * OUT_CH + col] = v;
            }
        }
    }
}

// ---------------- Launch: 6 dispatches (init, prep, offsets, fill, agg, gemm) ------

extern "C" void kernel_launch(void* const* d_in, const int* in_sizes, int n_in,
                              void* d_out, int out_size, void* d_ws, size_t ws_size,
                              hipStream_t stream) {
    const float* x     = (const float*)d_in[0];
    const int*   ei    = (const int*)d_in[1];
    const float* Wmsg  = (const float*)d_in[2];
    const float* bmsg  = (const float*)d_in[3];
    const float* Wroot = (const float*)d_in[4];
    const float* broot = (const float*)d_in[5];
    float* out = (float*)d_out;

    int N = in_sizes[0] / IN_CH;           // 50000
    int E = in_sizes[1] / 2;               // 600000
    int Mpad = 50176;                      // = 112*448 = 196*256
    if (N > Mpad) Mpad = ((N + 447) / 448) * 448;
    int MbP = (Mpad + GBMP - 1) / GBMP;    // 112 pipe blocks
    int MbS = (Mpad + GBM - 1) / GBM;      // fallback blocks
    int Sb = (N + 255) / 256;              // offsets blocks (196)
    int total4 = N * IN_CH / 4;

    char* ws = (char*)d_ws;
    size_t off = 0;
    auto alloc = [&](size_t bytes) -> void* {
        void* p = ws + off;
        off = (off + bytes + 255) & ~(size_t)255;
        return p;
    };
    size_t MpadA = (size_t)MbP * GBMP;
    if ((size_t)MbS * GBM > MpadA) MpadA = (size_t)MbS * GBM;
    int* degree  = (int*)alloc((size_t)N * 4);
    int* offsets = (int*)alloc((size_t)(N + 1) * 4);
    float* logsum = (float*)alloc(4);
    int* csr_src = (int*)alloc((size_t)E * 4);
    unsigned short* Whi = (unsigned short*)alloc((size_t)NGEMM * KDIM * 2);
    unsigned short* Wlo = (unsigned short*)alloc((size_t)NGEMM * KDIM * 2);
    unsigned short* Zhi = (unsigned short*)alloc(MpadA * KDIM * 2);
    unsigned short* xb  = (unsigned short*)alloc(MpadA * IN_CH * 2);
    float* ampv = (float*)alloc((size_t)N * 4);
    float* attv = (float*)alloc((size_t)N * 4);
    int MpadZ = (int)MpadA;

    // 1: init (zero degree/logsum + wbuild)
    int initg = (NGEMM * KDIM > N ? NGEMM * KDIM : N);
    init_kernel<<<(initg + 255) / 256, 256, 0, stream>>>(degree, logsum, Wmsg, Wroot,
                                                         Whi, Wlo, N);
    // 2: prep (degree atomics + xcast)
    int prepg = (max(E, total4) + 255) / 256;
    prep_kernel<<<prepg, 256, 0, stream>>>(ei, degree, x, xb, E, total4);
    // 3: offsets (scan via direct degree prefix, + logsum)
    offsets_kernel<<<Sb, 256, 0, stream>>>(degree, offsets, logsum, N, E);
    // 4: fill csr
    fill_kernel<<<(E + 255) / 256, 256, 0, stream>>>(ei, offsets, csr_src, E);
    // 5: agg
    agg_kernel<<<(MpadZ * 64 + 255) / 256, 256, 0, stream>>>(xb, csr_src, offsets, degree,
                                                             logsum, Zhi, ampv, attv, N, MpadZ);

    // 6: gemm (device-capability branch; capture-safe host queries)
    bool pipe = false;
    int dev = 0;
    if (hipGetDevice(&dev) == hipSuccess) {
        int optin = 0;
        if (hipDeviceGetAttribute(&optin, hipDeviceAttributeSharedMemPerBlockOptin, dev) == hipSuccess
            && optin >= (int)PIPE_LDS_BYTES) {
            pipe = (hipFuncSetAttribute((const void*)gemm_pipe,
                                        hipFuncAttributeMaxDynamicSharedMemorySize,
                                        PIPE_LDS_BYTES) == hipSuccess);
        }
    }
    if (pipe) {
        dim3 ggrid(MbP, 2);
        gemm_pipe<<<ggrid, 1024, PIPE_LDS_BYTES, stream>>>(Zhi, Whi, Wlo, ampv, attv,
                                                           bmsg, broot, out, N);
    } else {
        dim3 ggrid(MbS, 2);
        gemm_sb<<<ggrid, 1024, 0, stream>>>(Zhi, Whi, Wlo, ampv, attv,
                                            bmsg, broot, out, N);
    }
}